// Round 4
// baseline (25.534 us; speedup 1.0000x reference)
//
#include <hip/hip_runtime.h>

// Problem constants (match reference)
constexpr int B_IMG = 8;
constexpr int A_ANCH = 150000;
constexpr int C_CLS = 10;
constexpr int TPB = 256;
constexpr int APT = 4;    // anchors per thread: 40 attr floats = ten float4s in flight
constexpr int NBX = (A_ANCH + TPB * APT - 1) / (TPB * APT);   // 147

// ws layout: float att_part[B][NBX], rl_part[B][NBX], np_part[B][NBX]
__global__ __launch_bounds__(TPB) void focal_main(
    const float* __restrict__ attr,   // (B, A, C)
    const float* __restrict__ regr,   // (B, A, 4)
    const float* __restrict__ anch,   // (A, 4)
    const float* __restrict__ ann,    // (B, 14)
    float* __restrict__ att_part,
    float* __restrict__ rl_part,
    float* __restrict__ np_part)
{
    const int b = blockIdx.y;
    const int a0 = (blockIdx.x * TPB + threadIdx.x) * APT;
    const bool valid = (a0 < A_ANCH);   // A % 4 == 0, so a0 valid => a0..a0+3 valid

    // ---- issue ALL global loads for this thread upfront (12 independent float4s) ----
    float4 at4[10];   // 4 anchors x 10 classes = 40 floats
    float4 an4[4];    // 4 anchor boxes
    if (valid) {
        const float4* ap = reinterpret_cast<const float4*>(attr + ((size_t)b * A_ANCH + a0) * C_CLS);
#pragma unroll
        for (int j = 0; j < 10; ++j) at4[j] = ap[j];
        const float4* anp = reinterpret_cast<const float4*>(anch) + a0;
#pragma unroll
        for (int j = 0; j < 4; ++j) an4[j] = anp[j];
    }

    // annotation is wave-uniform -> scalar loads
    const float* annb = ann + b * 14;
    const float bx0 = annb[0], by0 = annb[1], bx1 = annb[2], by1 = annb[3];
    float lab[C_CLS];
#pragma unroll
    for (int c = 0; c < C_CLS; ++c) lab[c] = annb[4 + c];

    const float gw_raw = bx1 - bx0;
    const float gh_raw = by1 - by0;
    const float area = gw_raw * gh_raw;
    const float gcx = bx0 + 0.5f * gw_raw;
    const float gcy = by0 + 0.5f * gh_raw;
    const float gw = fmaxf(gw_raw, 1.0f);
    const float gh = fmaxf(gh_raw, 1.0f);

    const float TH  = (float)(1.0 / 9.0);
    const float SUB = (float)(0.5 / 9.0);
    const float PHI = (float)(1.0 - 0.0001);

    float att_sum = 0.0f;
    float rl_sum = 0.0f;
    int np = 0;

    if (valid) {
        float av[4 * C_CLS];
#pragma unroll
        for (int j = 0; j < 10; ++j) {
            av[4 * j + 0] = at4[j].x;
            av[4 * j + 1] = at4[j].y;
            av[4 * j + 2] = at4[j].z;
            av[4 * j + 3] = at4[j].w;
        }

#pragma unroll
        for (int k = 0; k < APT; ++k) {
            const float ax0 = an4[k].x, ay0 = an4[k].y, ax1 = an4[k].z, ay1 = an4[k].w;
            const float aw = ax1 - ax0;
            const float ah = ay1 - ay0;
            float iw = fminf(ax1, bx1) - fmaxf(ax0, bx0);
            float ih = fminf(ay1, by1) - fmaxf(ay0, by0);
            iw = fmaxf(iw, 0.0f);
            ih = fmaxf(ih, 0.0f);
            const float inter = iw * ih;
            const float uni = fmaxf(aw * ah + area - inter, 1e-8f);
            const float iou = inter / uni;
            const bool pos = (iou >= 0.5f);
            const bool neg = (iou < 0.4f);

            if (pos || neg) {
#pragma unroll
                for (int c = 0; c < C_CLS; ++c) {
                    float p = av[k * C_CLS + c];
                    p = fminf(fmaxf(p, 1e-4f), PHI);
                    const float tgt = pos ? lab[c] : 0.0f;
                    float loss;
                    if (tgt == 1.0f) {
                        const float q = 1.0f - p;
                        loss = 0.25f * (q * q) * (-logf(p));
                    } else {
                        loss = 0.75f * (p * p) * (-logf(1.0f - p));
                    }
                    att_sum += loss;
                }
            }
            if (pos) {
                ++np;
                const float acx = ax0 + 0.5f * aw;
                const float acy = ay0 + 0.5f * ah;
                const float t0 = ((gcx - acx) / aw) / 0.1f;
                const float t1 = ((gcy - acy) / ah) / 0.1f;
                const float t2 = logf(gw / aw) / 0.2f;
                const float t3 = logf(gh / ah) / 0.2f;
                const float4 r = *reinterpret_cast<const float4*>(regr + ((size_t)b * A_ANCH + a0 + k) * 4);
                float d;
                d = fabsf(t0 - r.x); rl_sum += (d <= TH) ? 4.5f * d * d : d - SUB;
                d = fabsf(t1 - r.y); rl_sum += (d <= TH) ? 4.5f * d * d : d - SUB;
                d = fabsf(t2 - r.z); rl_sum += (d <= TH) ? 4.5f * d * d : d - SUB;
                d = fabsf(t3 - r.w); rl_sum += (d <= TH) ? 4.5f * d * d : d - SUB;
            }
        }
    }

    // wave (64-lane) reduce
    float npf = (float)np;
#pragma unroll
    for (int off = 32; off > 0; off >>= 1) {
        att_sum += __shfl_down(att_sum, off);
        rl_sum  += __shfl_down(rl_sum, off);
        npf     += __shfl_down(npf, off);
    }

    __shared__ float s_att[TPB / 64];
    __shared__ float s_rl[TPB / 64];
    __shared__ float s_np[TPB / 64];
    const int wave = threadIdx.x >> 6;
    const int lane = threadIdx.x & 63;
    if (lane == 0) { s_att[wave] = att_sum; s_rl[wave] = rl_sum; s_np[wave] = npf; }
    __syncthreads();
    if (threadIdx.x == 0) {
        float a0s = 0.0f, r0 = 0.0f, n0 = 0.0f;
#pragma unroll
        for (int w = 0; w < TPB / 64; ++w) { a0s += s_att[w]; r0 += s_rl[w]; n0 += s_np[w]; }
        const int idx = b * NBX + blockIdx.x;
        att_part[idx] = a0s;            // plain stores, no atomics
        rl_part[idx]  = r0;
        np_part[idx]  = n0;             // counts < 2^24, exact in float
    }
}

// One block, 8 waves: wave b tree-reduces image b's NBX partials.
__global__ __launch_bounds__(512) void focal_finalize(
    const float* __restrict__ att_part,
    const float* __restrict__ rl_part,
    const float* __restrict__ np_part,
    float* __restrict__ out)
{
    const int wave = threadIdx.x >> 6;
    const int lane = threadIdx.x & 63;
    float as = 0.0f, rs = 0.0f, ns = 0.0f;
    if (wave < B_IMG) {
        for (int i = lane; i < NBX; i += 64) {
            as += att_part[wave * NBX + i];
            rs += rl_part[wave * NBX + i];
            ns += np_part[wave * NBX + i];
        }
    }
#pragma unroll
    for (int off = 32; off > 0; off >>= 1) {
        as += __shfl_down(as, off);
        rs += __shfl_down(rs, off);
        ns += __shfl_down(ns, off);
    }
    __shared__ float sa[B_IMG], sr[B_IMG], sn[B_IMG];
    if (lane == 0 && wave < B_IMG) { sa[wave] = as; sr[wave] = rs; sn[wave] = ns; }
    __syncthreads();
    if (threadIdx.x == 0) {
        double am = 0.0, rm = 0.0;
        for (int b = 0; b < B_IMG; ++b) {
            const double npd = (double)sn[b];
            const double npf = npd > 0.0 ? npd : 1.0;
            am += (double)sa[b] / npf;
            if (npd > 0.0) rm += (double)sr[b] / (npf * 4.0);
        }
        out[0] = (float)(am / (double)B_IMG);
        out[1] = (float)(rm / (double)B_IMG);
    }
}

extern "C" void kernel_launch(void* const* d_in, const int* in_sizes, int n_in,
                              void* d_out, int out_size, void* d_ws, size_t ws_size,
                              hipStream_t stream) {
    const float* attr = (const float*)d_in[0];   // attributes (B,A,C)
    const float* regr = (const float*)d_in[1];   // regressions (B,A,4)
    const float* anch = (const float*)d_in[2];   // anchors (1,A,4)
    const float* ann  = (const float*)d_in[3];   // annotations (B,14)
    float* out = (float*)d_out;

    float* att_part = (float*)d_ws;
    float* rl_part  = att_part + B_IMG * NBX;
    float* np_part  = rl_part + B_IMG * NBX;
    // All partials are stored unconditionally every launch -> no memset needed.

    dim3 grid(NBX, B_IMG);
    focal_main<<<grid, TPB, 0, stream>>>(attr, regr, anch, ann, att_part, rl_part, np_part);
    focal_finalize<<<1, 512, 0, stream>>>(att_part, rl_part, np_part, out);
}

// Round 5
// 24.886 us; speedup vs baseline: 1.0260x; 1.0260x over previous
//
#include <hip/hip_runtime.h>

// Problem constants (match reference)
constexpr int B_IMG = 8;
constexpr int A_ANCH = 150000;
constexpr int C_CLS = 10;
constexpr int TPB = 256;
constexpr int BA = TPB * 2;                       // anchors per block = 512 (APT=2)
constexpr int NBX = (A_ANCH + BA - 1) / BA;       // 293
constexpr int F4_PER_IMG = A_ANCH * C_CLS / 4;    // 375000 float4s per image
constexpr int F4_PER_BLK = BA * C_CLS / 4;        // 1280
constexpr int FLT_PER_BLK = BA * C_CLS;           // 5120

// ws layout: float att_part[B][NBX], rl_part[B][NBX], np_part[B][NBX]
__global__ __launch_bounds__(TPB) void focal_main(
    const float* __restrict__ attr,   // (B, A, C)
    const float* __restrict__ regr,   // (B, A, 4)
    const float* __restrict__ anch,   // (A, 4)
    const float* __restrict__ ann,    // (B, 14)
    float* __restrict__ att_part,
    float* __restrict__ rl_part,
    float* __restrict__ np_part)
{
    // Transposed attr tile: [class][anchor-local]. 10*512*4 = 20 KB.
    // Read phase: ds_read_b64 (anchor pair, one class) at lane-stride 2 dwords
    // -> 64 lanes span exactly 128 dwords = 4 full bank phases, conflict-free.
    __shared__ float sAttr[C_CLS * BA];

    const int b = blockIdx.y;
    const int tid = threadIdx.x;

    // ---- stage attributes: fully-coalesced float4 loads -> LDS transpose ----
    {
        const float4* ap = reinterpret_cast<const float4*>(attr) + (size_t)b * F4_PER_IMG;
        const int blkF4 = blockIdx.x * F4_PER_BLK;
#pragma unroll
        for (int j = 0; j < 5; ++j) {
            int f4 = blkF4 + j * TPB + tid;
            f4 = (f4 < F4_PER_IMG) ? f4 : (F4_PER_IMG - 1);   // clamp (dup writes are same-value)
            const float4 v = ap[f4];
            const unsigned l0 = (unsigned)(f4 * 4 - blockIdx.x * FLT_PER_BLK); // 0..5119
            const float vv[4] = {v.x, v.y, v.z, v.w};
#pragma unroll
            for (int d = 0; d < 4; ++d) {
                const unsigned l = l0 + d;
                sAttr[(l % 10u) * BA + (l / 10u)] = vv[d];
            }
        }
    }

    // ---- per-thread anchor pair: geometry loads (coalesced enough, 32B stride) ----
    const int a0 = blockIdx.x * BA + tid * 2;
    const bool valid = (a0 < A_ANCH);   // a0 even -> a0+1 also valid when a0 is

    float4 anA = make_float4(0.f, 0.f, 0.f, 0.f);
    float4 anB = anA;
    if (valid) {
        const float4* anp = reinterpret_cast<const float4*>(anch) + a0;
        anA = anp[0];
        anB = anp[1];
    }

    // annotation: wave-uniform scalar loads
    const float* annb = ann + b * 14;
    const float bx0 = annb[0], by0 = annb[1], bx1 = annb[2], by1 = annb[3];
    float lab[C_CLS];
#pragma unroll
    for (int c = 0; c < C_CLS; ++c) lab[c] = annb[4 + c];

    const float gw_raw = bx1 - bx0;
    const float gh_raw = by1 - by0;
    const float area = gw_raw * gh_raw;
    const float gcx = bx0 + 0.5f * gw_raw;
    const float gcy = by0 + 0.5f * gh_raw;
    const float gw = fmaxf(gw_raw, 1.0f);
    const float gh = fmaxf(gh_raw, 1.0f);

    const float TH  = (float)(1.0 / 9.0);
    const float SUB = (float)(0.5 / 9.0);
    const float PHI = (float)(1.0 - 0.0001);

    __syncthreads();   // attr tile ready

    float att_sum = 0.0f;
    float rl_sum = 0.0f;
    float npf = 0.0f;

    if (valid) {
        // IoU flags for both anchors of the pair
        bool pos[2], neg[2];
        float aw[2], ah[2], ax0v[2], ay0v[2];
        const float4 an[2] = {anA, anB};
#pragma unroll
        for (int k = 0; k < 2; ++k) {
            ax0v[k] = an[k].x; ay0v[k] = an[k].y;
            aw[k] = an[k].z - an[k].x;
            ah[k] = an[k].w - an[k].y;
            float iw = fminf(an[k].z, bx1) - fmaxf(an[k].x, bx0);
            float ih = fminf(an[k].w, by1) - fmaxf(an[k].y, by0);
            iw = fmaxf(iw, 0.0f);
            ih = fmaxf(ih, 0.0f);
            const float inter = iw * ih;
            const float uni = fmaxf(aw[k] * ah[k] + area - inter, 1e-8f);
            const float iou = inter / uni;
            pos[k] = (iou >= 0.5f);
            neg[k] = (iou < 0.4f);
        }
        const bool act0 = pos[0] || neg[0];
        const bool act1 = pos[1] || neg[1];
        const bool wave_has_pos = __any(pos[0] || pos[1]);   // wave-uniform branch

        const float2* row = reinterpret_cast<const float2*>(sAttr) + tid;  // + c*(BA/2)

        if (act0 || act1) {
            if (!wave_has_pos) {
                // fast path: every active anchor is negative -> targets all 0 -> one log
#pragma unroll
                for (int c = 0; c < C_CLS; ++c) {
                    const float2 pv = row[c * (BA / 2)];
                    if (act0) {
                        const float p = fminf(fmaxf(pv.x, 1e-4f), PHI);
                        att_sum += 0.75f * p * p * (-logf(1.0f - p));
                    }
                    if (act1) {
                        const float p = fminf(fmaxf(pv.y, 1e-4f), PHI);
                        att_sum += 0.75f * p * p * (-logf(1.0f - p));
                    }
                }
            } else {
                // general path (rare waves near the GT box)
#pragma unroll
                for (int c = 0; c < C_CLS; ++c) {
                    const float2 pv = row[c * (BA / 2)];
                    const float pp[2] = {pv.x, pv.y};
#pragma unroll
                    for (int k = 0; k < 2; ++k) {
                        const bool act = k ? act1 : act0;
                        if (act) {
                            const float p = fminf(fmaxf(pp[k], 1e-4f), PHI);
                            const float tgt = pos[k] ? lab[c] : 0.0f;
                            float loss;
                            if (tgt == 1.0f) {
                                const float q = 1.0f - p;
                                loss = 0.25f * (q * q) * (-logf(p));
                            } else {
                                loss = 0.75f * (p * p) * (-logf(1.0f - p));
                            }
                            att_sum += loss;
                        }
                    }
                }
            }
        }

        // regression loss: pos anchors only (rare)
#pragma unroll
        for (int k = 0; k < 2; ++k) {
            if (pos[k]) {
                npf += 1.0f;
                const float acx = ax0v[k] + 0.5f * aw[k];
                const float acy = ay0v[k] + 0.5f * ah[k];
                const float t0 = ((gcx - acx) / aw[k]) / 0.1f;
                const float t1 = ((gcy - acy) / ah[k]) / 0.1f;
                const float t2 = logf(gw / aw[k]) / 0.2f;
                const float t3 = logf(gh / ah[k]) / 0.2f;
                const float4 r = *reinterpret_cast<const float4*>(regr + ((size_t)b * A_ANCH + a0 + k) * 4);
                float d;
                d = fabsf(t0 - r.x); rl_sum += (d <= TH) ? 4.5f * d * d : d - SUB;
                d = fabsf(t1 - r.y); rl_sum += (d <= TH) ? 4.5f * d * d : d - SUB;
                d = fabsf(t2 - r.z); rl_sum += (d <= TH) ? 4.5f * d * d : d - SUB;
                d = fabsf(t3 - r.w); rl_sum += (d <= TH) ? 4.5f * d * d : d - SUB;
            }
        }
    }

    // wave (64-lane) reduce
#pragma unroll
    for (int off = 32; off > 0; off >>= 1) {
        att_sum += __shfl_down(att_sum, off);
        rl_sum  += __shfl_down(rl_sum, off);
        npf     += __shfl_down(npf, off);
    }

    __shared__ float s_att[TPB / 64];
    __shared__ float s_rl[TPB / 64];
    __shared__ float s_np[TPB / 64];
    const int wave = tid >> 6;
    const int lane = tid & 63;
    if (lane == 0) { s_att[wave] = att_sum; s_rl[wave] = rl_sum; s_np[wave] = npf; }
    __syncthreads();
    if (tid == 0) {
        float a0s = 0.0f, r0 = 0.0f, n0 = 0.0f;
#pragma unroll
        for (int w = 0; w < TPB / 64; ++w) { a0s += s_att[w]; r0 += s_rl[w]; n0 += s_np[w]; }
        const int idx = b * NBX + blockIdx.x;
        att_part[idx] = a0s;            // plain stores, no atomics
        rl_part[idx]  = r0;
        np_part[idx]  = n0;             // counts < 2^24, exact in float
    }
}

// One block, 8 waves: wave b tree-reduces image b's NBX partials.
__global__ __launch_bounds__(512) void focal_finalize(
    const float* __restrict__ att_part,
    const float* __restrict__ rl_part,
    const float* __restrict__ np_part,
    float* __restrict__ out)
{
    const int wave = threadIdx.x >> 6;
    const int lane = threadIdx.x & 63;
    float as = 0.0f, rs = 0.0f, ns = 0.0f;
    if (wave < B_IMG) {
        for (int i = lane; i < NBX; i += 64) {
            as += att_part[wave * NBX + i];
            rs += rl_part[wave * NBX + i];
            ns += np_part[wave * NBX + i];
        }
    }
#pragma unroll
    for (int off = 32; off > 0; off >>= 1) {
        as += __shfl_down(as, off);
        rs += __shfl_down(rs, off);
        ns += __shfl_down(ns, off);
    }
    __shared__ float sa[B_IMG], sr[B_IMG], sn[B_IMG];
    if (lane == 0 && wave < B_IMG) { sa[wave] = as; sr[wave] = rs; sn[wave] = ns; }
    __syncthreads();
    if (threadIdx.x == 0) {
        double am = 0.0, rm = 0.0;
        for (int b = 0; b < B_IMG; ++b) {
            const double npd = (double)sn[b];
            const double npf = npd > 0.0 ? npd : 1.0;
            am += (double)sa[b] / npf;
            if (npd > 0.0) rm += (double)sr[b] / (npf * 4.0);
        }
        out[0] = (float)(am / (double)B_IMG);
        out[1] = (float)(rm / (double)B_IMG);
    }
}

extern "C" void kernel_launch(void* const* d_in, const int* in_sizes, int n_in,
                              void* d_out, int out_size, void* d_ws, size_t ws_size,
                              hipStream_t stream) {
    const float* attr = (const float*)d_in[0];   // attributes (B,A,C)
    const float* regr = (const float*)d_in[1];   // regressions (B,A,4)
    const float* anch = (const float*)d_in[2];   // anchors (1,A,4)
    const float* ann  = (const float*)d_in[3];   // annotations (B,14)
    float* out = (float*)d_out;

    float* att_part = (float*)d_ws;
    float* rl_part  = att_part + B_IMG * NBX;
    float* np_part  = rl_part + B_IMG * NBX;
    // All partials are stored unconditionally every launch -> no memset needed.

    dim3 grid(NBX, B_IMG);
    focal_main<<<grid, TPB, 0, stream>>>(attr, regr, anch, ann, att_part, rl_part, np_part);
    focal_finalize<<<1, 512, 0, stream>>>(att_part, rl_part, np_part, out);
}